// Round 9
// baseline (64.436 us; speedup 1.0000x reference)
//
#include <hip/hip_runtime.h>
#include <hip/hip_bf16.h>
#include <stdint.h>

typedef __attribute__((ext_vector_type(8))) __bf16 bf16x8;
typedef __attribute__((ext_vector_type(4))) float f32x4;
typedef __attribute__((ext_vector_type(8))) unsigned short u16x8;

__device__ __forceinline__ unsigned short f2bf(float f) {
    unsigned u = __builtin_bit_cast(unsigned, f);
    return (unsigned short)((u + 0x7fffu + ((u >> 16) & 1u)) >> 16);  // RNE
}

__device__ __forceinline__ void glds16(const void* g, void* l) {
    __builtin_amdgcn_global_load_lds(
        (const __attribute__((address_space(1))) unsigned int*)(uintptr_t)g,
        (__attribute__((address_space(3))) unsigned int*)l, 16, 0, 0);
}

#define VMCNT(n) asm volatile("s_waitcnt vmcnt(" #n ")" ::: "memory")
#define BAR()                                  \
    do {                                       \
        asm volatile("" ::: "memory");         \
        __builtin_amdgcn_s_barrier();          \
        asm volatile("" ::: "memory");         \
    } while (0)

// ---------------------------------------------------------------------------
// Kernel 1 (fused prep): blocks [0,1024) build W; blocks [1024,5120) cvt x.
// Build: block (bo, bn4, wn) computes slabs IN LDS, does the 256x64x16 MFMA
// patch, stores 4 complete W rows.  (BISECTION: this is R8's prep_fused,
// unchanged; paired with R7's verified gemm to isolate R8's failure.)
//   W[(o01*64+o23)][(a01*64+a23)], o01=bo*4+w, o23=bn4*4+wn.
// factors layout: [b][j][i][o][r] strides b:512 j:128 i:16 o:2 r:1
// ---------------------------------------------------------------------------
__global__ __launch_bounds__(256) void prep_fused(const float* __restrict__ factors,
                                                  const float* __restrict__ cores,
                                                  const float4* __restrict__ xin,
                                                  ushort4* __restrict__ xb,
                                                  unsigned short* __restrict__ Wt) {
    if (blockIdx.x >= 1024) {
        // ---- cvt part: f32 -> bf16, 4096 blocks ----
        int i = (blockIdx.x - 1024) * 256 + threadIdx.x;
        float4 v = xin[i];
        ushort4 o;
        o.x = f2bf(v.x); o.y = f2bf(v.y); o.z = f2bf(v.z); o.w = f2bf(v.w);
        xb[i] = o;
        return;
    }
    // ---- build part: 1024 blocks ----
    __shared__ unsigned short As2[256 * 40];     // rows padded to 40 elems
    __shared__ unsigned short Bs2[64 * 40];
    __shared__ unsigned short lbuf[4 * 64 * 72];
    const int tid = threadIdx.x, lane = tid & 63, w = tid >> 6;
    const int bo = blockIdx.x >> 6, bn4 = (blockIdx.x >> 2) & 15, wn = blockIdx.x & 3;

    {   // As2 row tid: val = F0[a0,o0,r0]*F1[a1,o1,r1], k = b*4+q (16 + 16 zero)
        int o01 = bo * 4 + (tid >> 6), a01 = tid & 63;
        int o0 = o01 >> 3, o1 = o01 & 7, a0 = a01 >> 3, a1 = a01 & 7;
#pragma unroll
        for (int k = 0; k < 16; ++k) {
            int b = k >> 2, q = k & 3, r0 = q >> 1, r1 = q & 1;
            float v = factors[b*512 +   0 + a0*16 + o0*2 + r0]
                    * factors[b*512 + 128 + a1*16 + o1*2 + r1];
            As2[tid * 40 + k] = f2bf(v);
            As2[tid * 40 + 16 + k] = 0;
        }
    }
    {   // Bs2: 64 rows (a23) x 16 k; o23 fixed = bn4*4+wn
        int o23 = bn4 * 4 + wn, o2 = o23 >> 3, o3 = o23 & 7;
#pragma unroll
        for (int rep = 0; rep < 4; ++rep) {
            int task = rep * 256 + tid;          // 0..1023
            int n = task >> 4, k = task & 15;
            int a2 = n >> 3, a3 = n & 7;
            int b = k >> 2, q = k & 3, r0 = q >> 1, r1 = q & 1;
            float s = 0.f;
#pragma unroll
            for (int r2 = 0; r2 < 2; ++r2)
#pragma unroll
                for (int r3 = 0; r3 < 2; ++r3)
                    s += factors[b*512 + 256 + a2*16 + o2*2 + r2]
                       * factors[b*512 + 384 + a3*16 + o3*2 + r3]
                       * cores[b*16 + r3*8 + r2*4 + r1*2 + r0];
            Bs2[n * 40 + k] = f2bf(s);
            Bs2[n * 40 + 16 + k] = 0;
        }
    }
    __syncthreads();

    const int fr = lane & 15, fh = lane >> 4;
    bf16x8 af[4], bf_[4];
#pragma unroll
    for (int mf = 0; mf < 4; ++mf)
        af[mf] = *(const bf16x8*)&As2[(w * 64 + mf * 16 + fr) * 40 + fh * 8];
#pragma unroll
    for (int nf = 0; nf < 4; ++nf)
        bf_[nf] = *(const bf16x8*)&Bs2[(nf * 16 + fr) * 40 + fh * 8];
    f32x4 acc[4][4] = {};
#pragma unroll
    for (int mf = 0; mf < 4; ++mf)
#pragma unroll
        for (int nf = 0; nf < 4; ++nf)
            acc[mf][nf] = __builtin_amdgcn_mfma_f32_16x16x32_bf16(
                af[mf], bf_[nf], acc[mf][nf], 0, 0, 0);
    // wave w's 64x64 patch = full 4096 cols of W row o (i = a01*64 + a23)
#pragma unroll
    for (int mf = 0; mf < 4; ++mf)
#pragma unroll
        for (int nf = 0; nf < 4; ++nf)
#pragma unroll
            for (int j = 0; j < 4; ++j)
                lbuf[w * 4608 + (mf * 16 + fh * 4 + j) * 72 + nf * 16 + fr] =
                    f2bf(acc[mf][nf][j]);
    // same-wave LDS RAW: compiler inserts lgkmcnt waits
    const int o = (bo * 4 + w) * 64 + bn4 * 4 + wn;
    unsigned short* dst = Wt + (size_t)o * 4096;
#pragma unroll
    for (int i = 0; i < 8; ++i) {
        int c = i * 64 + lane;                   // 16B chunk 0..511 of the row
        *(u16x8*)&dst[c * 8] =
            *(const u16x8*)&lbuf[w * 4608 + (c >> 3) * 72 + (c & 7) * 8];
    }
}

// ---------------------------------------------------------------------------
// Kernel 2: C[1024][4096] = A[1024][4096] * Wt^T.  EXACT copy of R7's
// verified gemm_bt64 (45 us, MfmaUtil 30.6%, conflicts 0, absmax 9.3e-10):
//   tile 64(M) x 128(N), BK=64, 4 waves (2x2), wave-tile 32x64, acc 2x4.
//   Grid 512 = 2 desync blocks/CU; LDS 3 x 24KB; depth-2 pipeline,
//   counted vmcnt(12); plain f32 stores; source-side XOR chunk swizzle
//   (key (row>>1)&7); XCD map: xcd owns 4 bn (4MB W L2-resident).
// ---------------------------------------------------------------------------
__global__ __launch_bounds__(256, 2) void gemm_bt64(const unsigned short* __restrict__ A,
                                                    const unsigned short* __restrict__ Bt,
                                                    float* __restrict__ C) {
    constexpr int K = 4096;
    constexpr int N = 4096;
    constexpr int BK = 64;
    constexpr int NT = K / BK;                   // 64 K-steps
    __shared__ alignas(16) char lds[3][24576];   // [buf][A 8KB | B 16KB]
    const int tid = threadIdx.x;
    const int lane = tid & 63, w = tid >> 6;
    const int wm = w >> 1, wn = w & 1;
    const int xcd = blockIdx.x & 7, r = blockIdx.x >> 3;  // r 0..63
    const int bn = xcd * 4 + (r & 3);            // 0..31
    const int bm = r >> 2;                       // 0..15

    // --- staging: A = 512 16B slots (2/thread), B = 1024 (4/thread) ---
    const unsigned short* gA[2]; const unsigned short* gB[4];
    int lAoff[2], lBoff[4];
#pragma unroll
    for (int i = 0; i < 2; ++i) {
        int cs = i * 256 + tid;
        int row = cs >> 3;
        int c = (cs & 7) ^ ((row >> 1) & 7);
        gA[i] = A + (size_t)(bm * 64 + row) * K + c * 8;
        lAoff[i] = i * 4096 + w * 1024;          // wave-uniform base (+lane*16 HW)
    }
#pragma unroll
    for (int i = 0; i < 4; ++i) {
        int cs = i * 256 + tid;
        int row = cs >> 3;
        int c = (cs & 7) ^ ((row >> 1) & 7);
        gB[i] = Bt + (size_t)(bn * 128 + row) * K + c * 8;
        lBoff[i] = 8192 + i * 4096 + w * 1024;
    }

#define STAGE(buf, kt)                                                        \
    do {                                                                      \
        _Pragma("unroll")                                                     \
        for (int i = 0; i < 2; ++i) glds16(gA[i] + (kt), &lds[buf][lAoff[i]]);\
        _Pragma("unroll")                                                     \
        for (int i = 0; i < 4; ++i) glds16(gB[i] + (kt), &lds[buf][lBoff[i]]);\
    } while (0)

    // --- fragment read offsets (swizzled) ---
    const int fr = lane & 15, fh = lane >> 4;
    const int sk = (fr >> 1) & 7;
    int aoff[2], boff[2];
#pragma unroll
    for (int kk = 0; kk < 2; ++kk) {
        aoff[kk] = (wm * 32 + fr) * 128 + (((kk * 4 + fh) ^ sk) << 4);
        boff[kk] = 8192 + (wn * 64 + fr) * 128 + (((kk * 4 + fh) ^ sk) << 4);
    }

    f32x4 acc[2][4] = {};

#define COMPUTE(buf)                                                          \
    do {                                                                      \
        const char* base = &lds[buf][0];                                      \
        _Pragma("unroll")                                                     \
        for (int kk = 0; kk < 2; ++kk) {                                      \
            bf16x8 af2[2], bf4[4];                                            \
            _Pragma("unroll")                                                 \
            for (int m = 0; m < 2; ++m)                                       \
                af2[m] = *(const bf16x8*)(base + aoff[kk] + m * 2048);        \
            _Pragma("unroll")                                                 \
            for (int n = 0; n < 4; ++n)                                       \
                bf4[n] = *(const bf16x8*)(base + boff[kk] + n * 2048);        \
            _Pragma("unroll")                                                 \
            for (int m = 0; m < 2; ++m)                                       \
                _Pragma("unroll")                                             \
                for (int n = 0; n < 4; ++n)                                   \
                    acc[m][n] = __builtin_amdgcn_mfma_f32_16x16x32_bf16(      \
                        af2[m], bf4[n], acc[m][n], 0, 0, 0);                  \
        }                                                                     \
    } while (0)

#define PHASE(tb, sbuf, cbuf)                                                 \
    do {                                                                      \
        STAGE(sbuf, ((tb) + 2) * BK);                                         \
        VMCNT(12);                                                            \
        BAR();                                                                \
        COMPUTE(cbuf);                                                        \
        BAR();                                                                \
    } while (0)

    // --- depth-2 pipelined main loop (STAGE(s) targets buf s%3) ---
    STAGE(0, 0);
    STAGE(1, BK);
    for (int t = 0; t < 60; t += 3) {            // phases t, t+1, t+2
        PHASE(t, 2, 0);
        PHASE(t + 1, 0, 1);
        PHASE(t + 2, 1, 2);
    }
    PHASE(60, 2, 0);                             // stage 62, compute 60
    PHASE(61, 0, 1);                             // stage 63, compute 61
    VMCNT(6);  BAR(); COMPUTE(2); BAR();         // compute 62
    VMCNT(0);  BAR(); COMPUTE(0);                // compute 63

    // --- epilogue: plain coalesced stores ---
    const int crow0 = bm * 64 + wm * 32 + fh * 4;
    const int ccol0 = bn * 128 + wn * 64 + fr;
#pragma unroll
    for (int m = 0; m < 2; ++m)
#pragma unroll
        for (int n = 0; n < 4; ++n)
#pragma unroll
            for (int j = 0; j < 4; ++j)
                C[(size_t)(crow0 + m * 16 + j) * N + (ccol0 + n * 16)] = acc[m][n][j];
#undef STAGE
#undef COMPUTE
#undef PHASE
}

// ---------------------------------------------------------------------------
extern "C" void kernel_launch(void* const* d_in, const int* in_sizes, int n_in,
                              void* d_out, int out_size, void* d_ws, size_t ws_size,
                              hipStream_t stream) {
    const float* inputs  = (const float*)d_in[0];   // [1024, 4096] f32
    const float* cores   = (const float*)d_in[1];   // [4, 16] f32
    const float* factors = (const float*)d_in[2];   // [4,4,8,8,2] f32
    float* out = (float*)d_out;                     // [1024, 4096] f32

    char* ws = (char*)d_ws;
    unsigned short* xb = (unsigned short*)ws;                       //  8 MB bf16 x
    unsigned short* Wt = (unsigned short*)(ws + (8u << 20));        // 32 MB bf16 W^T

    prep_fused<<<5120, 256, 0, stream>>>(factors, cores,
                                         (const float4*)inputs, (ushort4*)xb, Wt);
    gemm_bt64<<<512, 256, 0, stream>>>(xb, Wt, out);
}